// Round 15
// baseline (383.055 us; speedup 1.0000x reference)
//
#include <hip/hip_runtime.h>
#include <stdint.h>

// Problem constants
#define MA    50
#define NGF   30
#define NAF   75
#define NA    6400
#define H     100
#define RPB   32          // rows per block (2 MFMA M-tiles of 16)
#define NTHR  512         // 8 waves
#define NT0P  8           // W0 N-tiles padded (7 real + 1 zero; zero tile skipped in C)
#define KT0   52          // W0 K-tiles (3 af + 49 slots)
#define NT1   2           // W1 N-tiles
#define KT1   4           // W1 K-tiles
#define AFW   104         // afh row stride (96 + 8) f16
#define HHW   136         // hh row stride (128 + 8) f16
#define KREGS 16          // kt (per K-half) held in registers for npair<3 waves

typedef _Float16 f16;
typedef _Float16 f16x8 __attribute__((ext_vector_type(8)));
typedef float    f32x4 __attribute__((ext_vector_type(4)));

#define MFMA16(a, b, c) __builtin_amdgcn_mfma_f32_16x16x32_f16((a), (b), (c), 0, 0, 0)

// ---- fused prep: block 0 = mask-dtype detect; blocks 1..104 = pack W0;
// ---- blocks 105,106 = pack W1 (hi + scaled lo)
__global__ void prep(const float* __restrict__ W0, const float* __restrict__ W1,
                     const uint8_t* __restrict__ cm,
                     f16* __restrict__ w0h, f16* __restrict__ w1h, f16* __restrict__ w1l,
                     int* __restrict__ flag) {
    const int bid = blockIdx.x;
    const int tidb = threadIdx.x;
    if (bid == 0) {
        if (tidb < 64) {
            int any = 0;
            #pragma unroll
            for (int i = 0; i < 64; ++i) {
                int pos = i * 64 + tidb;
                if ((pos & 3) != 0 && cm[pos] != 0) any = 1;
            }
            unsigned long long b = __ballot(any != 0);
            if (tidb == 0) *flag = (b != 0ULL) ? 1 : 0;
        }
        return;
    }
    if (bid <= 104) {
        int idx = (bid - 1) * 256 + tidb;            // [nt][kt][lane]
        int lane = idx & 63;
        int ktn  = idx >> 6;
        int nt = ktn / KT0, kt = ktn % KT0;
        int col = nt * 16 + (lane & 15);
        #pragma unroll
        for (int e = 0; e < 8; ++e) {
            int k = kt * 32 + (lane >> 4) * 8 + e;
            int kr = -1;
            if (kt < 3) { if (k < NAF) kr = k; }
            else {
                int kk = k - kt * 32;
                if (kk < NGF) kr = NAF + (kt - 3) * NGF + kk;
            }
            float wv = (kr >= 0 && col < H) ? W0[(size_t)kr * H + col] : 0.f;
            w0h[(size_t)idx * 8 + e] = (f16)wv;
        }
        return;
    }
    {
        int idx = (bid - 105) * 256 + tidb;
        if (idx >= NT1 * KT1 * 64) return;
        int lane = idx & 63;
        int ktn  = idx >> 6;
        int nt = ktn / KT1, kt = ktn % KT1;
        int col = nt * 16 + (lane & 15);
        #pragma unroll
        for (int e = 0; e < 8; ++e) {
            int k = kt * 32 + (lane >> 4) * 8 + e;
            float wv = (k < H && col < NGF) ? W1[(size_t)k * NGF + col] : 0.f;
            f16 hi = (f16)wv;
            w1h[(size_t)idx * 8 + e] = hi;
            w1l[(size_t)idx * 8 + e] = (f16)((wv - (float)hi) * 1024.f);
        }
    }
}

// 1 block/CU (LDS 142.6KB). waves_per_eu(2,2) tells the allocator max
// occupancy is 2 waves/SIMD -> 256-VGPR budget (default heuristic caps at
// 128 and SPILLS any reg-resident-B attempt: rounds 3/6/10/11).
__global__ void __launch_bounds__(NTHR)
__attribute__((amdgpu_waves_per_eu(2, 2)))
dag_mfma(
    const float* __restrict__ af,      // (NA, NAF) f32
    const int*   __restrict__ parents, // (NA, MA, MA)
    const int*   __restrict__ orders,  // (NA, MA)
    const void*  __restrict__ cmask,   // (NA, MA)
    const float* __restrict__ b0,
    const float* __restrict__ b1,
    const f16*   __restrict__ w0h,
    const f16*   __restrict__ w1h, const f16* __restrict__ w1l,
    const int*   __restrict__ flagp,
    float*       __restrict__ dout)    // (NA, NGF)
{
    // gf state: slot-major [51][32 rows][32 f16], full-address element-XOR
    // swizzle  addr = (slot*1024 + r*32 + c) ^ ((r&7)<<3), write==read semantics.
    // 5-phase loop (A/B/C/R/D/E) kept EXACTLY as round 8/14 — the 4-phase
    // fold-scatter variant measured +50us (rounds 12/13 A/B).
    __shared__ f16     gfh[51 * 1024];     // 104,448 B
    __shared__ f16     afh[RPB][AFW];      //   6,656 B
    __shared__ f16     hh[RPB][HHW];       //   8,704 B
    __shared__ f32x4   part[4][2][2][64];  //  16,384 B  K-half partials
    __shared__ float   outl[RPB][33];      //   4,224 B
    __shared__ uint8_t slots[RPB][52];     //   1,664 B
    __shared__ int     colc[RPB];          //     128 B
    __shared__ int     maskc[RPB];         //     128 B
    __shared__ int     ordl[2][RPB];       //     256 B
    // total ~142.6 KB -> 1 block/CU, 8 waves

    const int tid   = threadIdx.x;
    const int w     = tid >> 6;
    const int lane  = tid & 63;
    const int mrow  = lane & 15;   // row within M-tile / output col
    const int kg    = lane >> 4;   // k-octet group
    const int npair = w & 3;       // N-tile pair index (nt = 2*npair, 2*npair+1)
    const int half  = w >> 2;      // K-half (0: kt 0..25, 1: kt 26..51)
    const int row0  = blockIdx.x * RPB;
    const int flag  = *flagp;

    // swizzled per-lane gfh bases (FULL-address XOR, matching the write path)
    const int base0 = (mrow * 32 + kg * 8) ^ ((mrow & 7) << 3);
    const int base1 = ((16 + mrow) * 32 + kg * 8) ^ ((mrow & 7) << 3);

    // per-lane bias constants
    const int hc0 = npair * 32 + mrow;        // half=0 waves: h cols
    const int hc1 = npair * 32 + 16 + mrow;
    const float b0v0 = (w < 4 && hc0 < H) ? b0[hc0] : 0.f;
    const float b0v1 = (w < 4 && hc1 < H) ? b0[hc1] : 0.f;
    const int oc = (w - 4) * 16 + mrow;       // waves 4,5: out col
    const float b1v = (w >= 4 && w < 6 && oc < NGF) ? b1[oc] : 0.f;

    // B-fragment pointers (per wave), and the register-resident subset:
    // npair<3 : wr[2q],wr[2q+1] = (nt0,nt1) frag for kt q (q<KREGS of my half)
    // npair==3: wr[q] = nt=6 frag for kt q (all 26 of my half; nt=7 zero-skip)
    const f16x8* B0 = (const f16x8*)w0h + ((size_t)(2 * npair) * KT0 + half * 26) * 64 + lane;
    const f16x8* B1 = B0 + (size_t)KT0 * 64;
    f16x8 wr[2 * KREGS];
    if (npair < 3) {
        #pragma unroll
        for (int q = 0; q < KREGS; ++q) {
            wr[2 * q]     = B0[(size_t)q * 64];
            wr[2 * q + 1] = B1[(size_t)q * 64];
        }
    } else {
        #pragma unroll
        for (int q = 0; q < 26; ++q) wr[q] = B0[(size_t)q * 64];
    }

    // ---- zero LDS state (pads stay zero forever) ----
    {
        f16x8 z = 0;
        for (int e = tid; e < 51 * 128; e += NTHR) ((f16x8*)gfh)[e] = z;
        for (int e = tid; e < RPB * AFW / 8; e += NTHR) ((f16x8*)&afh[0][0])[e] = z;
        for (int e = tid; e < RPB * HHW / 8; e += NTHR) ((f16x8*)&hh[0][0])[e]  = z;
    }
    if (tid >= 384 && tid < 416) {
        int r = tid - 384;
        ordl[0][r] = orders[(size_t)(row0 + r) * MA];
    }
    __syncthreads();

    float afr0 = 0.f, afr1 = 0.f, afr2 = 0.f, afr3 = 0.f, afr4 = 0.f;
    int   slr0 = 0, slr1 = 0, slr2 = 0, slr3 = 0;
    int   colr = 0, mskr = 0, oreg = 0;

    // issue gather loads for step T into regs (af rows via ordl[T&1])
    auto LOADS = [&](int T) {
        const int* ordb = ordl[T & 1];
        {
            int idx, r, k;
            idx = tid;        r = idx / NAF; k = idx - r * NAF; afr0 = af[(size_t)ordb[r] * NAF + k];
            idx = tid + 512;  r = idx / NAF; k = idx - r * NAF; afr1 = af[(size_t)ordb[r] * NAF + k];
            idx = tid + 1024; r = idx / NAF; k = idx - r * NAF; afr2 = af[(size_t)ordb[r] * NAF + k];
            idx = tid + 1536; r = idx / NAF; k = idx - r * NAF; afr3 = af[(size_t)ordb[r] * NAF + k];
            if (tid < 352) {
                idx = tid + 2048; r = idx / NAF; k = idx - r * NAF;
                afr4 = af[(size_t)ordb[r] * NAF + k];
            }
        }
        {
            int idx, r, p;
            idx = tid;        r = idx / 49; p = idx - r * 49;
            slr0 = __builtin_nontemporal_load(&parents[((size_t)(row0 + r) * MA + T) * MA + 1 + p]);
            idx = tid + 512;  r = idx / 49; p = idx - r * 49;
            slr1 = __builtin_nontemporal_load(&parents[((size_t)(row0 + r) * MA + T) * MA + 1 + p]);
            idx = tid + 1024; r = idx / 49; p = idx - r * 49;
            slr2 = __builtin_nontemporal_load(&parents[((size_t)(row0 + r) * MA + T) * MA + 1 + p]);
            if (tid < 32) {
                idx = tid + 1536; r = idx / 49; p = idx - r * 49;
                slr3 = __builtin_nontemporal_load(&parents[((size_t)(row0 + r) * MA + T) * MA + 1 + p]);
            }
        }
        if (tid >= 416 && tid < 448) {
            int r = tid - 416;
            colr = __builtin_nontemporal_load(&parents[((size_t)(row0 + r) * MA + T) * MA]);
        }
        if (tid >= 448 && tid < 480) {
            int r = tid - 448;
            if (flag) mskr = (int)__builtin_nontemporal_load(&((const uint8_t*)cmask)[(size_t)(row0 + r) * MA + T]);
            else      mskr = __builtin_nontemporal_load(&((const int*)cmask)[(size_t)(row0 + r) * MA + T]);
        }
        if (T + 1 < MA && tid >= 384 && tid < 416) {
            int r = tid - 384;
            oreg = __builtin_nontemporal_load(&orders[(size_t)(row0 + r) * MA + T + 1]);
        }
    };

    LOADS(0);

    for (int t = 0; t < MA; ++t) {
        // ---- phase A: commit staged gather(t) to LDS ----
        {
            int idx, r, k;
            idx = tid;        r = idx / NAF; k = idx - r * NAF; afh[r][k] = (f16)afr0;
            idx = tid + 512;  r = idx / NAF; k = idx - r * NAF; afh[r][k] = (f16)afr1;
            idx = tid + 1024; r = idx / NAF; k = idx - r * NAF; afh[r][k] = (f16)afr2;
            idx = tid + 1536; r = idx / NAF; k = idx - r * NAF; afh[r][k] = (f16)afr3;
            if (tid < 352) { idx = tid + 2048; r = idx / NAF; k = idx - r * NAF; afh[r][k] = (f16)afr4; }
        }
        {
            int idx, r, p;
            idx = tid;        r = idx / 49; p = idx - r * 49; slots[r][p] = (uint8_t)slr0;
            idx = tid + 512;  r = idx / 49; p = idx - r * 49; slots[r][p] = (uint8_t)slr1;
            idx = tid + 1024; r = idx / 49; p = idx - r * 49; slots[r][p] = (uint8_t)slr2;
            if (tid < 32) { idx = tid + 1536; r = idx / 49; p = idx - r * 49; slots[r][p] = (uint8_t)slr3; }
        }
        if (tid >= 416 && tid < 448) colc[tid - 416]  = colr;
        if (tid >= 448 && tid < 480) maskc[tid - 448] = mskr;
        if (t + 1 < MA && tid >= 384 && tid < 416) ordl[(t + 1) & 1][tid - 384] = oreg;
        __syncthreads();

        // ---- phase B: issue gather loads for t+1 (hidden under MFMA) ----
        if (t + 1 < MA) LOADS(t + 1);

        // ---- phase C: all 8 waves, K-split GEMM; B = regs (kt<KREGS) + L2 stream.
        // npair<3: J=2 (nt=2np, 2np+1). npair==3: J=1 (nt=6; nt=7 zero-skip). ----
        f32x4 acc00 = {0.f,0.f,0.f,0.f}, acc01 = {0.f,0.f,0.f,0.f};
        f32x4 acc10 = {0.f,0.f,0.f,0.f}, acc11 = {0.f,0.f,0.f,0.f};
        if (npair < 3) {
            if (half == 0) {
                #pragma unroll
                for (int kt = 0; kt < 3; ++kt) {     // atom-feature k-tiles (regs)
                    f16x8 a0 = *(const f16x8*)&afh[mrow][kt * 32 + kg * 8];
                    f16x8 a1 = *(const f16x8*)&afh[16 + mrow][kt * 32 + kg * 8];
                    f16x8 bb0 = wr[2 * kt];
                    f16x8 bb1 = wr[2 * kt + 1];
                    acc00 = MFMA16(a0, bb0, acc00); acc10 = MFMA16(a1, bb0, acc10);
                    acc01 = MFMA16(a0, bb1, acc01); acc11 = MFMA16(a1, bb1, acc11);
                }
                #pragma unroll
                for (int g = 0; g < 23; ++g) {       // slots p=g, kt=3+g
                    const int kt = 3 + g;
                    int s0 = slots[mrow][g];
                    int s1 = slots[16 + mrow][g];
                    f16x8 a0 = *(const f16x8*)&gfh[s0 * 1024 + base0];
                    f16x8 a1 = *(const f16x8*)&gfh[s1 * 1024 + base1];
                    f16x8 bb0, bb1;
                    if (kt < KREGS) { bb0 = wr[2 * kt]; bb1 = wr[2 * kt + 1]; }
                    else            { bb0 = B0[(size_t)kt * 64]; bb1 = B1[(size_t)kt * 64]; }
                    acc00 = MFMA16(a0, bb0, acc00); acc10 = MFMA16(a1, bb0, acc10);
                    acc01 = MFMA16(a0, bb1, acc01); acc11 = MFMA16(a1, bb1, acc11);
                }
            } else {
                #pragma unroll
                for (int g = 0; g < 26; ++g) {       // slots p=23+g, kt-within-half=g
                    int s0 = slots[mrow][23 + g];
                    int s1 = slots[16 + mrow][23 + g];
                    f16x8 a0 = *(const f16x8*)&gfh[s0 * 1024 + base0];
                    f16x8 a1 = *(const f16x8*)&gfh[s1 * 1024 + base1];
                    f16x8 bb0, bb1;
                    if (g < KREGS) { bb0 = wr[2 * g]; bb1 = wr[2 * g + 1]; }
                    else           { bb0 = B0[(size_t)g * 64]; bb1 = B1[(size_t)g * 64]; }
                    acc00 = MFMA16(a0, bb0, acc00); acc10 = MFMA16(a1, bb0, acc10);
                    acc01 = MFMA16(a0, bb1, acc01); acc11 = MFMA16(a1, bb1, acc11);
                }
            }
        } else {
            if (half == 0) {
                #pragma unroll
                for (int kt = 0; kt < 3; ++kt) {
                    f16x8 a0 = *(const f16x8*)&afh[mrow][kt * 32 + kg * 8];
                    f16x8 a1 = *(const f16x8*)&afh[16 + mrow][kt * 32 + kg * 8];
                    f16x8 bb0 = wr[kt];
                    acc00 = MFMA16(a0, bb0, acc00); acc10 = MFMA16(a1, bb0, acc10);
                }
                #pragma unroll
                for (int g = 0; g < 23; ++g) {
                    int s0 = slots[mrow][g];
                    int s1 = slots[16 + mrow][g];
                    f16x8 a0 = *(const f16x8*)&gfh[s0 * 1024 + base0];
                    f16x8 a1 = *(const f16x8*)&gfh[s1 * 1024 + base1];
                    f16x8 bb0 = wr[3 + g];
                    acc00 = MFMA16(a0, bb0, acc00); acc10 = MFMA16(a1, bb0, acc10);
                }
            } else {
                #pragma unroll
                for (int g = 0; g < 26; ++g) {
                    int s0 = slots[mrow][23 + g];
                    int s1 = slots[16 + mrow][23 + g];
                    f16x8 a0 = *(const f16x8*)&gfh[s0 * 1024 + base0];
                    f16x8 a1 = *(const f16x8*)&gfh[s1 * 1024 + base1];
                    f16x8 bb0 = wr[g];
                    acc00 = MFMA16(a0, bb0, acc00); acc10 = MFMA16(a1, bb0, acc10);
                }
            }
        }
        if (half) {
            part[npair][0][0][lane] = acc00;
            part[npair][0][1][lane] = acc01;
            part[npair][1][0][lane] = acc10;
            part[npair][1][1][lane] = acc11;
        }
        __syncthreads();

        // ---- phase R: half=0 waves reduce K-halves, bias+relu, write hh ----
        if (!half) {
            acc00 += part[npair][0][0][lane];
            acc01 += part[npair][0][1][lane];
            acc10 += part[npair][1][0][lane];
            acc11 += part[npair][1][1][lane];
            #pragma unroll
            for (int i = 0; i < 4; ++i) {
                hh[kg * 4 + i][hc0]      = (f16)fmaxf(acc00[i] + b0v0, 0.f);
                hh[kg * 4 + i][hc1]      = (f16)fmaxf(acc01[i] + b0v1, 0.f);
                hh[16 + kg * 4 + i][hc0] = (f16)fmaxf(acc10[i] + b0v0, 0.f);
                hh[16 + kg * 4 + i][hc1] = (f16)fmaxf(acc11[i] + b0v1, 0.f);
            }
        }
        __syncthreads();

        // ---- phase D: waves 4,5: out = relu(h @ W1 + b1) (hi/lo) ----
        if (w == 4 || w == 5) {
            const int nt2 = w - 4;
            f32x4 h00 = {0.f,0.f,0.f,0.f}, l00 = {0.f,0.f,0.f,0.f};
            f32x4 h10 = {0.f,0.f,0.f,0.f}, l10 = {0.f,0.f,0.f,0.f};
            const f16x8* Bh = (const f16x8*)w1h + (size_t)nt2 * KT1 * 64 + lane;
            const f16x8* Bl = (const f16x8*)w1l + (size_t)nt2 * KT1 * 64 + lane;
            #pragma unroll
            for (int kt = 0; kt < KT1; ++kt) {
                f16x8 a0  = *(const f16x8*)&hh[mrow][kt * 32 + kg * 8];
                f16x8 a1  = *(const f16x8*)&hh[16 + mrow][kt * 32 + kg * 8];
                f16x8 bhf = Bh[(size_t)kt * 64];
                f16x8 blf = Bl[(size_t)kt * 64];
                h00 = MFMA16(a0, bhf, h00); l00 = MFMA16(a0, blf, l00);
                h10 = MFMA16(a1, bhf, h10); l10 = MFMA16(a1, blf, l10);
            }
            if (oc < NGF) {
                #pragma unroll
                for (int i = 0; i < 4; ++i) {
                    outl[kg * 4 + i][oc]      = fmaxf(h00[i] + l00[i] * (1.f/1024.f) + b1v, 0.f);
                    outl[16 + kg * 4 + i][oc] = fmaxf(h10[i] + l10[i] * (1.f/1024.f) + b1v, 0.f);
                }
            }
        }
        __syncthreads();

        // ---- phase E: masked scatter into swizzled gfh; final dout at t=49 ----
        {
            int e = tid;
            #pragma unroll
            for (int q = 0; q < 2; ++q, e += NTHR) {
                if (e < RPB * NGF) {
                    int r = e / NGF, c = e - r * NGF;
                    float v = outl[r][c];
                    if (maskc[r])
                        gfh[(colc[r] * 1024 + r * 32 + c) ^ ((r & 7) << 3)] = (f16)v;
                    if (t == MA - 1)
                        dout[(size_t)(row0 + r) * NGF + c] = maskc[r] ? v : 0.f;
                }
            }
        }
        __syncthreads();
    }
}

extern "C" void kernel_launch(void* const* d_in, const int* in_sizes, int n_in,
                              void* d_out, int out_size, void* d_ws, size_t ws_size,
                              hipStream_t stream) {
    const float* af      = (const float*)d_in[0];
    const int*   parents = (const int*)  d_in[1];
    const int*   orders  = (const int*)  d_in[2];
    const void*  cmask   =               d_in[3];
    // d_in[4] = n_atoms scalar, unused
    const float* W0      = (const float*)d_in[5];
    const float* b0      = (const float*)d_in[6];
    const float* W1      = (const float*)d_in[7];
    const float* b1      = (const float*)d_in[8];

    char* ws = (char*)d_ws;
    f16* w0h = (f16*)(ws);               // 8*52*64*8*2 = 425,984 B
    f16* w1h = (f16*)(ws + 425984);      //   8,192 B
    f16* w1l = (f16*)(ws + 434176);      //   8,192 B
    int* flagp = (int*)(ws + 442368);
    float* dout = (float*)d_out;

    prep<<<107, 256, 0, stream>>>(W0, W1, (const uint8_t*)cmask, w0h, w1h, w1l, flagp);

    dag_mfma<<<NA / RPB, NTHR, 0, stream>>>(
        af, parents, orders, cmask, b0, b1, w0h, w1h, w1l, flagp, dout);
}

// Round 16
// 280.033 us; speedup vs baseline: 1.3679x; 1.3679x over previous
//
#include <hip/hip_runtime.h>
#include <stdint.h>

// Problem constants
#define MA    50
#define NGF   30
#define NAF   75
#define NA    6400
#define H     100
#define RPB   32          // rows per block (2 MFMA M-tiles of 16)
#define NTHR  512         // 8 waves
#define NT0P  8           // W0 N-tiles padded (7 real + 1 zero; zero tile skipped in C)
#define KT0   52          // W0 K-tiles (3 af + 49 slots)
#define NT1   2           // W1 N-tiles
#define KT1   4           // W1 K-tiles
#define AFW   104         // afh row stride (96 + 8) f16
#define HHW   136         // hh row stride (128 + 8) f16

typedef _Float16 f16;
typedef _Float16 f16x8 __attribute__((ext_vector_type(8)));
typedef float    f32x4 __attribute__((ext_vector_type(4)));

#define MFMA16(a, b, c) __builtin_amdgcn_mfma_f32_16x16x32_f16((a), (b), (c), 0, 0, 0)

// ---- fused prep: block 0 = mask-dtype detect; blocks 1..104 = pack W0;
// ---- blocks 105,106 = pack W1 (hi + scaled lo)
__global__ void prep(const float* __restrict__ W0, const float* __restrict__ W1,
                     const uint8_t* __restrict__ cm,
                     f16* __restrict__ w0h, f16* __restrict__ w1h, f16* __restrict__ w1l,
                     int* __restrict__ flag) {
    const int bid = blockIdx.x;
    const int tidb = threadIdx.x;
    if (bid == 0) {
        if (tidb < 64) {
            int any = 0;
            #pragma unroll
            for (int i = 0; i < 64; ++i) {
                int pos = i * 64 + tidb;
                if ((pos & 3) != 0 && cm[pos] != 0) any = 1;
            }
            unsigned long long b = __ballot(any != 0);
            if (tidb == 0) *flag = (b != 0ULL) ? 1 : 0;
        }
        return;
    }
    if (bid <= 104) {
        int idx = (bid - 1) * 256 + tidb;            // [nt][kt][lane]
        int lane = idx & 63;
        int ktn  = idx >> 6;
        int nt = ktn / KT0, kt = ktn % KT0;
        int col = nt * 16 + (lane & 15);
        #pragma unroll
        for (int e = 0; e < 8; ++e) {
            int k = kt * 32 + (lane >> 4) * 8 + e;
            int kr = -1;
            if (kt < 3) { if (k < NAF) kr = k; }
            else {
                int kk = k - kt * 32;
                if (kk < NGF) kr = NAF + (kt - 3) * NGF + kk;
            }
            float wv = (kr >= 0 && col < H) ? W0[(size_t)kr * H + col] : 0.f;
            w0h[(size_t)idx * 8 + e] = (f16)wv;
        }
        return;
    }
    {
        int idx = (bid - 105) * 256 + tidb;
        if (idx >= NT1 * KT1 * 64) return;
        int lane = idx & 63;
        int ktn  = idx >> 6;
        int nt = ktn / KT1, kt = ktn % KT1;
        int col = nt * 16 + (lane & 15);
        #pragma unroll
        for (int e = 0; e < 8; ++e) {
            int k = kt * 32 + (lane >> 4) * 8 + e;
            float wv = (k < H && col < NGF) ? W1[(size_t)k * NGF + col] : 0.f;
            f16 hi = (f16)wv;
            w1h[(size_t)idx * 8 + e] = hi;
            w1l[(size_t)idx * 8 + e] = (f16)((wv - (float)hi) * 1024.f);
        }
    }
}

__global__ __launch_bounds__(NTHR, 2) void dag_mfma(
    const float* __restrict__ af,      // (NA, NAF) f32
    const int*   __restrict__ parents, // (NA, MA, MA)
    const int*   __restrict__ orders,  // (NA, MA)
    const void*  __restrict__ cmask,   // (NA, MA)
    const float* __restrict__ b0,
    const float* __restrict__ b1,
    const f16*   __restrict__ w0h,
    const f16*   __restrict__ w1h, const f16* __restrict__ w1l,
    const int*   __restrict__ flagp,
    float*       __restrict__ dout)    // (NA, NGF)
{
    // gf state: slot-major [51][32 rows][32 f16], full-address element-XOR
    // swizzle  addr = (slot*1024 + r*32 + c) ^ ((r&7)<<3), write==read semantics.
    // 5-phase loop (A/B/C/R/D/E) kept EXACTLY as round 8 — the 4-phase
    // fold-scatter variant measured +50us (rounds 12/13 A/B). B streams from
    // L2 — register-resident B is allocator-unreachable (r3/6/10/11/15).
    __shared__ f16     gfh[51 * 1024];     // 104,448 B
    __shared__ f16     afh[RPB][AFW];      //   6,656 B
    __shared__ f16     hh[RPB][HHW];       //   8,704 B
    __shared__ f32x4   part[4][2][2][64];  //  16,384 B  K-half partials
    __shared__ float   outl[RPB][33];      //   4,224 B
    __shared__ uint8_t slots[RPB][52];     //   1,664 B
    __shared__ int     colc[RPB];          //     128 B
    __shared__ int     maskc[RPB];         //     128 B
    __shared__ int     ordl[2][RPB];       //     256 B
    // total ~142.6 KB -> 1 block/CU, 8 waves

    const int tid   = threadIdx.x;
    const int w     = tid >> 6;
    const int lane  = tid & 63;
    const int mrow  = lane & 15;   // row within M-tile / output col
    const int kg    = lane >> 4;   // k-octet group
    const int npair = w & 3;       // N-tile pair index (nt = 2*npair, 2*npair+1)
    const int half  = w >> 2;      // K-half (0: kt 0..25, 1: kt 26..51)
    const int row0  = blockIdx.x * RPB;
    const int flag  = *flagp;

    // swizzled per-lane gfh bases (FULL-address XOR, matching the write path)
    const int base0 = (mrow * 32 + kg * 8) ^ ((mrow & 7) << 3);
    const int base1 = ((16 + mrow) * 32 + kg * 8) ^ ((mrow & 7) << 3);

    // per-lane bias constants
    const int hc0 = npair * 32 + mrow;        // half=0 waves: h cols
    const int hc1 = npair * 32 + 16 + mrow;
    const float b0v0 = (w < 4 && hc0 < H) ? b0[hc0] : 0.f;
    const float b0v1 = (w < 4 && hc1 < H) ? b0[hc1] : 0.f;
    const int oc = (w - 4) * 16 + mrow;       // waves 4,5: out col
    const float b1v = (w >= 4 && w < 6 && oc < NGF) ? b1[oc] : 0.f;

    // ---- zero LDS state (pads stay zero forever) ----
    {
        f16x8 z = 0;
        for (int e = tid; e < 51 * 128; e += NTHR) ((f16x8*)gfh)[e] = z;
        for (int e = tid; e < RPB * AFW / 8; e += NTHR) ((f16x8*)&afh[0][0])[e] = z;
        for (int e = tid; e < RPB * HHW / 8; e += NTHR) ((f16x8*)&hh[0][0])[e]  = z;
    }
    if (tid >= 384 && tid < 416) {
        int r = tid - 384;
        ordl[0][r] = orders[(size_t)(row0 + r) * MA];
    }
    __syncthreads();

    float afr0 = 0.f, afr1 = 0.f, afr2 = 0.f, afr3 = 0.f, afr4 = 0.f;
    int   slr0 = 0, slr1 = 0, slr2 = 0, slr3 = 0;
    int   colr = 0, mskr = 0, oreg = 0;

    // issue gather loads for step T into regs (af rows via ordl[T&1])
    auto LOADS = [&](int T) {
        const int* ordb = ordl[T & 1];
        {
            int idx, r, k;
            idx = tid;        r = idx / NAF; k = idx - r * NAF; afr0 = af[(size_t)ordb[r] * NAF + k];
            idx = tid + 512;  r = idx / NAF; k = idx - r * NAF; afr1 = af[(size_t)ordb[r] * NAF + k];
            idx = tid + 1024; r = idx / NAF; k = idx - r * NAF; afr2 = af[(size_t)ordb[r] * NAF + k];
            idx = tid + 1536; r = idx / NAF; k = idx - r * NAF; afr3 = af[(size_t)ordb[r] * NAF + k];
            if (tid < 352) {
                idx = tid + 2048; r = idx / NAF; k = idx - r * NAF;
                afr4 = af[(size_t)ordb[r] * NAF + k];
            }
        }
        {
            int idx, r, p;
            idx = tid;        r = idx / 49; p = idx - r * 49;
            slr0 = __builtin_nontemporal_load(&parents[((size_t)(row0 + r) * MA + T) * MA + 1 + p]);
            idx = tid + 512;  r = idx / 49; p = idx - r * 49;
            slr1 = __builtin_nontemporal_load(&parents[((size_t)(row0 + r) * MA + T) * MA + 1 + p]);
            idx = tid + 1024; r = idx / 49; p = idx - r * 49;
            slr2 = __builtin_nontemporal_load(&parents[((size_t)(row0 + r) * MA + T) * MA + 1 + p]);
            if (tid < 32) {
                idx = tid + 1536; r = idx / 49; p = idx - r * 49;
                slr3 = __builtin_nontemporal_load(&parents[((size_t)(row0 + r) * MA + T) * MA + 1 + p]);
            }
        }
        if (tid >= 416 && tid < 448) {
            int r = tid - 416;
            colr = __builtin_nontemporal_load(&parents[((size_t)(row0 + r) * MA + T) * MA]);
        }
        if (tid >= 448 && tid < 480) {
            int r = tid - 448;
            if (flag) mskr = (int)__builtin_nontemporal_load(&((const uint8_t*)cmask)[(size_t)(row0 + r) * MA + T]);
            else      mskr = __builtin_nontemporal_load(&((const int*)cmask)[(size_t)(row0 + r) * MA + T]);
        }
        if (T + 1 < MA && tid >= 384 && tid < 416) {
            int r = tid - 384;
            oreg = __builtin_nontemporal_load(&orders[(size_t)(row0 + r) * MA + T + 1]);
        }
    };

    LOADS(0);

    for (int t = 0; t < MA; ++t) {
        // ---- phase A: commit staged gather(t) to LDS ----
        {
            int idx, r, k;
            idx = tid;        r = idx / NAF; k = idx - r * NAF; afh[r][k] = (f16)afr0;
            idx = tid + 512;  r = idx / NAF; k = idx - r * NAF; afh[r][k] = (f16)afr1;
            idx = tid + 1024; r = idx / NAF; k = idx - r * NAF; afh[r][k] = (f16)afr2;
            idx = tid + 1536; r = idx / NAF; k = idx - r * NAF; afh[r][k] = (f16)afr3;
            if (tid < 352) { idx = tid + 2048; r = idx / NAF; k = idx - r * NAF; afh[r][k] = (f16)afr4; }
        }
        {
            int idx, r, p;
            idx = tid;        r = idx / 49; p = idx - r * 49; slots[r][p] = (uint8_t)slr0;
            idx = tid + 512;  r = idx / 49; p = idx - r * 49; slots[r][p] = (uint8_t)slr1;
            idx = tid + 1024; r = idx / 49; p = idx - r * 49; slots[r][p] = (uint8_t)slr2;
            if (tid < 32) { idx = tid + 1536; r = idx / 49; p = idx - r * 49; slots[r][p] = (uint8_t)slr3; }
        }
        if (tid >= 416 && tid < 448) colc[tid - 416]  = colr;
        if (tid >= 448 && tid < 480) maskc[tid - 448] = mskr;
        if (t + 1 < MA && tid >= 384 && tid < 416) ordl[(t + 1) & 1][tid - 384] = oreg;
        __syncthreads();

        // ---- phase B: issue gather loads for t+1 (hidden under MFMA) ----
        if (t + 1 < MA) LOADS(t + 1);

        // ---- phase C: all 8 waves, K-split GEMM; B streamed from L2.
        // npair<3: J=2 (nt=2np, 2np+1). npair==3: J=1 (nt=6 only; nt=7 is the
        // zero-pad tile — skipping it cuts B traffic + MFMA count 12.5%). ----
        f32x4 acc00 = {0.f,0.f,0.f,0.f}, acc01 = {0.f,0.f,0.f,0.f};
        f32x4 acc10 = {0.f,0.f,0.f,0.f}, acc11 = {0.f,0.f,0.f,0.f};
        {
            const f16x8* B0 = (const f16x8*)w0h + ((size_t)(2 * npair) * KT0 + half * 26) * 64 + lane;
            const f16x8* B1 = B0 + (size_t)KT0 * 64;
            if (npair < 3) {
                if (half == 0) {
                    #pragma unroll
                    for (int kt = 0; kt < 3; ++kt) {     // atom-feature k-tiles
                        f16x8 a0 = *(const f16x8*)&afh[mrow][kt * 32 + kg * 8];
                        f16x8 a1 = *(const f16x8*)&afh[16 + mrow][kt * 32 + kg * 8];
                        f16x8 bb0 = B0[(size_t)kt * 64];
                        f16x8 bb1 = B1[(size_t)kt * 64];
                        acc00 = MFMA16(a0, bb0, acc00); acc10 = MFMA16(a1, bb0, acc10);
                        acc01 = MFMA16(a0, bb1, acc01); acc11 = MFMA16(a1, bb1, acc11);
                    }
                    #pragma unroll
                    for (int g = 0; g < 23; ++g) {       // slots p = 0..22 (kt 3..25)
                        int s0 = slots[mrow][g];
                        int s1 = slots[16 + mrow][g];
                        f16x8 a0 = *(const f16x8*)&gfh[s0 * 1024 + base0];
                        f16x8 a1 = *(const f16x8*)&gfh[s1 * 1024 + base1];
                        f16x8 bb0 = B0[(size_t)(3 + g) * 64];
                        f16x8 bb1 = B1[(size_t)(3 + g) * 64];
                        acc00 = MFMA16(a0, bb0, acc00); acc10 = MFMA16(a1, bb0, acc10);
                        acc01 = MFMA16(a0, bb1, acc01); acc11 = MFMA16(a1, bb1, acc11);
                    }
                } else {
                    #pragma unroll
                    for (int g = 0; g < 26; ++g) {       // slots p = 23..48 (kt 26..51)
                        int s0 = slots[mrow][23 + g];
                        int s1 = slots[16 + mrow][23 + g];
                        f16x8 a0 = *(const f16x8*)&gfh[s0 * 1024 + base0];
                        f16x8 a1 = *(const f16x8*)&gfh[s1 * 1024 + base1];
                        f16x8 bb0 = B0[(size_t)g * 64];
                        f16x8 bb1 = B1[(size_t)g * 64];
                        acc00 = MFMA16(a0, bb0, acc00); acc10 = MFMA16(a1, bb0, acc10);
                        acc01 = MFMA16(a0, bb1, acc01); acc11 = MFMA16(a1, bb1, acc11);
                    }
                }
            } else {
                if (half == 0) {
                    #pragma unroll
                    for (int kt = 0; kt < 3; ++kt) {
                        f16x8 a0 = *(const f16x8*)&afh[mrow][kt * 32 + kg * 8];
                        f16x8 a1 = *(const f16x8*)&afh[16 + mrow][kt * 32 + kg * 8];
                        f16x8 bb0 = B0[(size_t)kt * 64];
                        acc00 = MFMA16(a0, bb0, acc00); acc10 = MFMA16(a1, bb0, acc10);
                    }
                    #pragma unroll
                    for (int g = 0; g < 23; ++g) {
                        int s0 = slots[mrow][g];
                        int s1 = slots[16 + mrow][g];
                        f16x8 a0 = *(const f16x8*)&gfh[s0 * 1024 + base0];
                        f16x8 a1 = *(const f16x8*)&gfh[s1 * 1024 + base1];
                        f16x8 bb0 = B0[(size_t)(3 + g) * 64];
                        acc00 = MFMA16(a0, bb0, acc00); acc10 = MFMA16(a1, bb0, acc10);
                    }
                } else {
                    #pragma unroll
                    for (int g = 0; g < 26; ++g) {
                        int s0 = slots[mrow][23 + g];
                        int s1 = slots[16 + mrow][23 + g];
                        f16x8 a0 = *(const f16x8*)&gfh[s0 * 1024 + base0];
                        f16x8 a1 = *(const f16x8*)&gfh[s1 * 1024 + base1];
                        f16x8 bb0 = B0[(size_t)g * 64];
                        acc00 = MFMA16(a0, bb0, acc00); acc10 = MFMA16(a1, bb0, acc10);
                    }
                }
            }
        }
        if (half) {
            part[npair][0][0][lane] = acc00;
            part[npair][0][1][lane] = acc01;
            part[npair][1][0][lane] = acc10;
            part[npair][1][1][lane] = acc11;
        }
        __syncthreads();

        // ---- phase R: half=0 waves reduce K-halves, bias+relu, write hh ----
        if (!half) {
            acc00 += part[npair][0][0][lane];
            acc01 += part[npair][0][1][lane];
            acc10 += part[npair][1][0][lane];
            acc11 += part[npair][1][1][lane];
            #pragma unroll
            for (int i = 0; i < 4; ++i) {
                hh[kg * 4 + i][hc0]      = (f16)fmaxf(acc00[i] + b0v0, 0.f);
                hh[kg * 4 + i][hc1]      = (f16)fmaxf(acc01[i] + b0v1, 0.f);
                hh[16 + kg * 4 + i][hc0] = (f16)fmaxf(acc10[i] + b0v0, 0.f);
                hh[16 + kg * 4 + i][hc1] = (f16)fmaxf(acc11[i] + b0v1, 0.f);
            }
        }
        __syncthreads();

        // ---- phase D: waves 4,5: out = relu(h @ W1 + b1) (hi/lo) ----
        if (w == 4 || w == 5) {
            const int nt2 = w - 4;
            f32x4 h00 = {0.f,0.f,0.f,0.f}, l00 = {0.f,0.f,0.f,0.f};
            f32x4 h10 = {0.f,0.f,0.f,0.f}, l10 = {0.f,0.f,0.f,0.f};
            const f16x8* Bh = (const f16x8*)w1h + (size_t)nt2 * KT1 * 64 + lane;
            const f16x8* Bl = (const f16x8*)w1l + (size_t)nt2 * KT1 * 64 + lane;
            #pragma unroll
            for (int kt = 0; kt < KT1; ++kt) {
                f16x8 a0  = *(const f16x8*)&hh[mrow][kt * 32 + kg * 8];
                f16x8 a1  = *(const f16x8*)&hh[16 + mrow][kt * 32 + kg * 8];
                f16x8 bhf = Bh[(size_t)kt * 64];
                f16x8 blf = Bl[(size_t)kt * 64];
                h00 = MFMA16(a0, bhf, h00); l00 = MFMA16(a0, blf, l00);
                h10 = MFMA16(a1, bhf, h10); l10 = MFMA16(a1, blf, l10);
            }
            if (oc < NGF) {
                #pragma unroll
                for (int i = 0; i < 4; ++i) {
                    outl[kg * 4 + i][oc]      = fmaxf(h00[i] + l00[i] * (1.f/1024.f) + b1v, 0.f);
                    outl[16 + kg * 4 + i][oc] = fmaxf(h10[i] + l10[i] * (1.f/1024.f) + b1v, 0.f);
                }
            }
        }
        __syncthreads();

        // ---- phase E: masked scatter into swizzled gfh; final dout at t=49 ----
        {
            int e = tid;
            #pragma unroll
            for (int q = 0; q < 2; ++q, e += NTHR) {
                if (e < RPB * NGF) {
                    int r = e / NGF, c = e - r * NGF;
                    float v = outl[r][c];
                    if (maskc[r])
                        gfh[(colc[r] * 1024 + r * 32 + c) ^ ((r & 7) << 3)] = (f16)v;
                    if (t == MA - 1)
                        dout[(size_t)(row0 + r) * NGF + c] = maskc[r] ? v : 0.f;
                }
            }
        }
        __syncthreads();
    }
}

extern "C" void kernel_launch(void* const* d_in, const int* in_sizes, int n_in,
                              void* d_out, int out_size, void* d_ws, size_t ws_size,
                              hipStream_t stream) {
    const float* af      = (const float*)d_in[0];
    const int*   parents = (const int*)  d_in[1];
    const int*   orders  = (const int*)  d_in[2];
    const void*  cmask   =               d_in[3];
    // d_in[4] = n_atoms scalar, unused
    const float* W0      = (const float*)d_in[5];
    const float* b0      = (const float*)d_in[6];
    const float* W1      = (const float*)d_in[7];
    const float* b1      = (const float*)d_in[8];

    char* ws = (char*)d_ws;
    f16* w0h = (f16*)(ws);               // 8*52*64*8*2 = 425,984 B
    f16* w1h = (f16*)(ws + 425984);      //   8,192 B
    f16* w1l = (f16*)(ws + 434176);      //   8,192 B
    int* flagp = (int*)(ws + 442368);
    float* dout = (float*)d_out;

    prep<<<107, 256, 0, stream>>>(W0, W1, (const uint8_t*)cmask, w0h, w1h, w1l, flagp);

    dag_mfma<<<NA / RPB, NTHR, 0, stream>>>(
        af, parents, orders, cmask, b0, b1, w0h, w1h, w1l, flagp, dout);
}